// Round 1
// 240.396 us; speedup vs baseline: 1.0189x; 1.0189x over previous
//
#include <hip/hip_runtime.h>
#include <cstdint>
#include <cstddef>

// FusedBitLinear: RMSNorm -> ternary W quant (absmean) -> int8 activation quant
// -> int GEMM (MFMA i8) -> rescale by alpha*gamma[m]/127.
//
// M=4096 tokens, K=4096, N=4096. fp32 in/out.
//
// ws layout:
//   [0, 16M)            xq   int8 [4096][4096]
//   [16M, 32M)          wq   int8 [4096][4096]
//   [32M, +16KB)        gamma float[4096]
//   [+16KB, +32KB)      alpha partials float[4096]
//   [+32KB, +4B)        alpha float[1]

#define KD 4096
#define MD 4096
#define ND 4096

// W-quant streaming blocks (each thread: 32 float4 = 128 elems)
#define WBLK 512

typedef int i32x4 __attribute__((ext_vector_type(4)));

// async global->LDS, 16B per lane; lds dst is wave-uniform base (+lane*16)
__device__ __forceinline__ void gl2lds16(const signed char* g, signed char* l) {
  __builtin_amdgcn_global_load_lds(
      (const __attribute__((address_space(1))) void*)g,
      (__attribute__((address_space(3))) void*)l, 16, 0, 0);
}

__device__ __forceinline__ float wave_sum(float v) {
#pragma unroll
  for (int off = 32; off; off >>= 1) v += __shfl_down(v, off, 64);
  return v;
}
__device__ __forceinline__ float wave_max(float v) {
#pragma unroll
  for (int off = 32; off; off >>= 1) v = fmaxf(v, __shfl_down(v, off, 64));
  return v;
}

// ---------------- pass 1: per-row |W| partial sums ------------------------
// UNCHANGED from the 244 us kernel: part[] layout and reduction order feed a
// bit-identical alpha in pass 2.

__global__ __launch_bounds__(256) void k_alpha_part(const float* __restrict__ w,
                                                    float* __restrict__ part) {
  __shared__ float red[4];
  const int tid = threadIdx.x;
  const float4* w4 = (const float4*)(w + (size_t)blockIdx.x * 4096);
  float s = 0.f;
#pragma unroll
  for (int i = 0; i < 4; ++i) {
    float4 v = w4[i * 256 + tid];
    s += fabsf(v.x) + fabsf(v.y) + fabsf(v.z) + fabsf(v.w);
  }
  s = wave_sum(s);
  if ((tid & 63) == 0) red[tid >> 6] = s;
  __syncthreads();
  if (tid == 0) part[blockIdx.x] = (red[0] + red[1]) + (red[2] + red[3]);
}

// ---------------- pass 2: fused quantization ------------------------------
// blocks [0,4096): RMSNorm + gamma + int8 quant of x row bid. ONE fused
//   reduction round: (sum x^2, max|x*nw|) together; gamma = max|x*nw|/rms
//   (== max|x/rms*nw| mathematically; ulp-level difference only).
// blocks [4096, 4096+WBLK): recompute alpha from partials (bit-identical
//   reduction in every block -> deterministic), then grid-stride stream-quant
//   W: no per-row reduction is needed once alpha is known, so 512 blocks with
//   8x the per-block work amortize the alpha recompute and kill the per-row
//   startup latency the old 4096-block version paid.

__device__ __forceinline__ uint32_t qw4(float4 v, float alpha) {
  // EXACT same arithmetic as the 244 us kernel -> bit-identical wq.
  int q0 = (int)fminf(fmaxf(rintf(v.x / alpha), -1.f), 1.f);
  int q1 = (int)fminf(fmaxf(rintf(v.y / alpha), -1.f), 1.f);
  int q2 = (int)fminf(fmaxf(rintf(v.z / alpha), -1.f), 1.f);
  int q3 = (int)fminf(fmaxf(rintf(v.w / alpha), -1.f), 1.f);
  return (uint32_t)(q0 & 255) | ((uint32_t)(q1 & 255) << 8) |
         ((uint32_t)(q2 & 255) << 16) | ((uint32_t)(q3 & 255) << 24);
}

__global__ __launch_bounds__(256) void k_quant_all(const float* __restrict__ w,
                                                   const float* __restrict__ x,
                                                   const float* __restrict__ nw,
                                                   const float* __restrict__ part,
                                                   signed char* __restrict__ wq,
                                                   signed char* __restrict__ xq,
                                                   float* __restrict__ gamma,
                                                   float* __restrict__ alpha_out) {
  const int tid = threadIdx.x;
  const int bid = blockIdx.x;
  __shared__ float red[4];
  __shared__ float red2[4];

  if (bid < 4096) {
    // ---- RMSNorm + gamma + quantize x row (fused single reduction) ----
    const int row = bid;
    const float4* x4 = (const float4*)(x + (size_t)row * 4096);
    const float4* n4 = (const float4*)nw;
    float4 xv[4], nv[4];
#pragma unroll
    for (int i = 0; i < 4; ++i) {
      xv[i] = x4[i * 256 + tid];
      nv[i] = n4[i * 256 + tid];
    }
    float ss = 0.f, mx = 0.f;
#pragma unroll
    for (int i = 0; i < 4; ++i) {
      ss += xv[i].x * xv[i].x + xv[i].y * xv[i].y + xv[i].z * xv[i].z +
            xv[i].w * xv[i].w;
      mx = fmaxf(mx,
                 fmaxf(fmaxf(fabsf(xv[i].x * nv[i].x), fabsf(xv[i].y * nv[i].y)),
                       fmaxf(fabsf(xv[i].z * nv[i].z), fabsf(xv[i].w * nv[i].w))));
    }
    ss = wave_sum(ss);
    mx = wave_max(mx);
    if ((tid & 63) == 0) {
      red[tid >> 6] = ss;
      red2[tid >> 6] = mx;
    }
    __syncthreads();
    const float tot = (red[0] + red[1]) + (red[2] + red[3]);
    const float rms = sqrtf(tot * (1.0f / 4096.0f) + 1e-6f);
    const float mxr = fmaxf(fmaxf(red2[0], red2[1]), fmaxf(red2[2], red2[3]));
    const float g = fmaxf(mxr / rms, 1e-10f);
    if (tid == 0) gamma[row] = g;
    const float inv = 127.0f / (rms * g);

    uint32_t* xqi = (uint32_t*)(xq + (size_t)row * 4096);
#pragma unroll
    for (int i = 0; i < 4; ++i) {
      const int f = i * 256 + tid;
      int q0 = (int)fminf(fmaxf(rintf(xv[i].x * nv[i].x * inv), -128.f), 127.f);
      int q1 = (int)fminf(fmaxf(rintf(xv[i].y * nv[i].y * inv), -128.f), 127.f);
      int q2 = (int)fminf(fmaxf(rintf(xv[i].z * nv[i].z * inv), -128.f), 127.f);
      int q3 = (int)fminf(fmaxf(rintf(xv[i].w * nv[i].w * inv), -128.f), 127.f);
      xqi[f] = (uint32_t)(q0 & 255) | ((uint32_t)(q1 & 255) << 8) |
               ((uint32_t)(q2 & 255) << 16) | ((uint32_t)(q3 & 255) << 24);
    }
  } else {
    // ---- alpha finalize (same reduction order as before -> bit-identical)
    const int wb = bid - 4096;
    float s = 0.f;
#pragma unroll
    for (int i = 0; i < 16; ++i) s += part[i * 256 + tid];
    s = wave_sum(s);
    if ((tid & 63) == 0) red[tid >> 6] = s;
    __syncthreads();
    const float alpha =
        fmaxf(((red[0] + red[1]) + (red[2] + red[3])) * (1.0f / 16777216.0f),
              1e-10f);
    if (wb == 0 && tid == 0) alpha_out[0] = alpha;

    // ---- stream-quantize W: 512 blocks x 256 thr x 32 float4 ----
    const float4* w4 = (const float4*)w;
    uint32_t* wqi = (uint32_t*)wq;
#pragma unroll 1
    for (int k = 0; k < 32; k += 4) {
      const int f0 = (wb * 32 + k) * 256 + tid;
      float4 v0 = w4[f0];
      float4 v1 = w4[f0 + 256];
      float4 v2 = w4[f0 + 512];
      float4 v3 = w4[f0 + 768];
      wqi[f0] = qw4(v0, alpha);
      wqi[f0 + 256] = qw4(v1, alpha);
      wqi[f0 + 512] = qw4(v2, alpha);
      wqi[f0 + 768] = qw4(v3, alpha);
    }
  }
}

// ------------- int8 GEMM: y[m,n] = (xq . wq^T) * alpha*gamma[m]/127 -------
// UNCHANGED from the 244 us kernel (verified: 0 bank conflicts, 82.5 us).
// 128x128 block tile, BK=128 (32 KB LDS), 4 waves (2x2), each wave 64x64 via
// 4x4 MFMA 16x16x64 i8, two K-slices per staged tile -> 32 MFMA per barrier.

__global__ __launch_bounds__(256) void k_gemm(const signed char* __restrict__ xq,
                                              const signed char* __restrict__ wq,
                                              const float* __restrict__ gamma,
                                              const float* __restrict__ alpha_p,
                                              float* __restrict__ out) {
  __shared__ __align__(16) signed char As[128 * 128];
  __shared__ __align__(16) signed char Bs[128 * 128];
  const int tid = threadIdx.x;
  const int lane = tid & 63;
  const int wave = tid >> 6;
  const int wm = (wave >> 1) * 64;
  const int wn = (wave & 1) * 64;
  const int quad = lane >> 4;
  const int l16 = lane & 15;
  const int bm = blockIdx.y * 128;
  const int bn = blockIdx.x * 128;

  const signed char* Ag = xq + (size_t)bm * KD;
  const signed char* Bg = wq + (size_t)bn * KD;

  const int lr = lane >> 3;
  const int sc = (lane & 7) ^ lr;
  const signed char* agp[4];
  const signed char* bgp[4];
  signed char* la[4];
  signed char* lb[4];
#pragma unroll
  for (int i = 0; i < 4; ++i) {
    const int R = i * 32 + wave * 8 + lr;
    agp[i] = Ag + (size_t)R * KD + sc * 16;
    bgp[i] = Bg + (size_t)R * KD + sc * 16;
    la[i] = &As[(i * 32 + wave * 8) * 128];
    lb[i] = &Bs[(i * 32 + wave * 8) * 128];
  }

  i32x4 acc[4][4];
#pragma unroll
  for (int i = 0; i < 4; ++i)
#pragma unroll
    for (int j = 0; j < 4; ++j) acc[i][j] = (i32x4){0, 0, 0, 0};

  const int swz = l16 & 7;

  for (int k0 = 0; k0 < KD; k0 += 128) {
    __syncthreads();
#pragma unroll
    for (int i = 0; i < 4; ++i) gl2lds16(agp[i] + k0, la[i]);
#pragma unroll
    for (int i = 0; i < 4; ++i) gl2lds16(bgp[i] + k0, lb[i]);
    __syncthreads();

#pragma unroll
    for (int ks = 0; ks < 2; ++ks) {
      const int pos = ((ks * 4 + quad) ^ swz) * 16;
      i32x4 af[4], bf[4];
#pragma unroll
      for (int mi = 0; mi < 4; ++mi)
        af[mi] = *(const i32x4*)&As[(wm + mi * 16 + l16) * 128 + pos];
#pragma unroll
      for (int ni = 0; ni < 4; ++ni)
        bf[ni] = *(const i32x4*)&Bs[(wn + ni * 16 + l16) * 128 + pos];
#pragma unroll
      for (int mi = 0; mi < 4; ++mi)
#pragma unroll
        for (int ni = 0; ni < 4; ++ni)
          acc[mi][ni] = __builtin_amdgcn_mfma_i32_16x16x64_i8(af[mi], bf[ni],
                                                              acc[mi][ni], 0, 0, 0);
    }
  }

  const float alpha = alpha_p[0];
#pragma unroll
  for (int mi = 0; mi < 4; ++mi) {
#pragma unroll
    for (int r = 0; r < 4; ++r) {
      const int m = bm + wm + mi * 16 + quad * 4 + r;
      const float s = (alpha * gamma[m]) / 127.0f;
#pragma unroll
      for (int ni = 0; ni < 4; ++ni) {
        const int n = bn + wn + ni * 16 + l16;
        out[(size_t)m * ND + n] = (float)acc[mi][ni][r] * s;
      }
    }
  }
}

// --------------------------------------------------------------------------

extern "C" void kernel_launch(void* const* d_in, const int* in_sizes, int n_in,
                              void* d_out, int out_size, void* d_ws, size_t ws_size,
                              hipStream_t stream) {
  const float* x = (const float*)d_in[0];
  const float* w = (const float*)d_in[1];
  const float* nw = (const float*)d_in[2];
  float* out = (float*)d_out;

  char* ws = (char*)d_ws;
  signed char* xq = (signed char*)ws;
  signed char* wq = (signed char*)(ws + ((size_t)1 << 24));
  float* gamma = (float*)(ws + ((size_t)2 << 24));
  float* part = (float*)(ws + ((size_t)2 << 24) + 16384);
  float* alpha = (float*)(ws + ((size_t)2 << 24) + 32768);

  k_alpha_part<<<4096, 256, 0, stream>>>(w, part);
  k_quant_all<<<4096 + WBLK, 256, 0, stream>>>(w, x, nw, part, wq, xq, gamma, alpha);
  dim3 g(ND / 128, MD / 128);
  k_gemm<<<g, 256, 0, stream>>>(xq, wq, gamma, alpha, out);
}

// Round 3
// 235.868 us; speedup vs baseline: 1.0385x; 1.0192x over previous
//
#include <hip/hip_runtime.h>
#include <cstdint>
#include <cstddef>

// FusedBitLinear: RMSNorm -> ternary W quant (absmean) -> int8 activation quant
// -> int GEMM (MFMA i8) -> rescale by alpha*gamma[m]/127.
//
// M=4096 tokens, K=4096, N=4096. fp32 in/out.
//
// ws layout:
//   [0, 16M)            xq   int8 [4096][4096]
//   [16M, 32M)          wq   int8 [4096][4096]
//   [32M, +16KB)        gamma float[4096]
//   [+16KB, +32KB)      alpha partials float[4096]
//   [+32KB, +4B)        alpha float[1]

#define KD 4096
#define MD 4096
#define ND 4096

#define WBLK 512

typedef int i32x4 __attribute__((ext_vector_type(4)));

// async global->LDS, 16B per lane; lds dst is wave-uniform base (+lane*16)
__device__ __forceinline__ void gl2lds16(const signed char* g, signed char* l) {
  __builtin_amdgcn_global_load_lds(
      (const __attribute__((address_space(1))) void*)g,
      (__attribute__((address_space(3))) void*)l, 16, 0, 0);
}

__device__ __forceinline__ float wave_sum(float v) {
#pragma unroll
  for (int off = 32; off; off >>= 1) v += __shfl_down(v, off, 64);
  return v;
}
__device__ __forceinline__ float wave_max(float v) {
#pragma unroll
  for (int off = 32; off; off >>= 1) v = fmaxf(v, __shfl_down(v, off, 64));
  return v;
}

// ---------------- pass 1: per-row |W| partial sums (UNCHANGED) ------------

__global__ __launch_bounds__(256) void k_alpha_part(const float* __restrict__ w,
                                                    float* __restrict__ part) {
  __shared__ float red[4];
  const int tid = threadIdx.x;
  const float4* w4 = (const float4*)(w + (size_t)blockIdx.x * 4096);
  float s = 0.f;
#pragma unroll
  for (int i = 0; i < 4; ++i) {
    float4 v = w4[i * 256 + tid];
    s += fabsf(v.x) + fabsf(v.y) + fabsf(v.z) + fabsf(v.w);
  }
  s = wave_sum(s);
  if ((tid & 63) == 0) red[tid >> 6] = s;
  __syncthreads();
  if (tid == 0) part[blockIdx.x] = (red[0] + red[1]) + (red[2] + red[3]);
}

// ---------------- pass 2: fused quantization (UNCHANGED from round 1) -----

__device__ __forceinline__ uint32_t qw4(float4 v, float alpha) {
  int q0 = (int)fminf(fmaxf(rintf(v.x / alpha), -1.f), 1.f);
  int q1 = (int)fminf(fmaxf(rintf(v.y / alpha), -1.f), 1.f);
  int q2 = (int)fminf(fmaxf(rintf(v.z / alpha), -1.f), 1.f);
  int q3 = (int)fminf(fmaxf(rintf(v.w / alpha), -1.f), 1.f);
  return (uint32_t)(q0 & 255) | ((uint32_t)(q1 & 255) << 8) |
         ((uint32_t)(q2 & 255) << 16) | ((uint32_t)(q3 & 255) << 24);
}

__global__ __launch_bounds__(256) void k_quant_all(const float* __restrict__ w,
                                                   const float* __restrict__ x,
                                                   const float* __restrict__ nw,
                                                   const float* __restrict__ part,
                                                   signed char* __restrict__ wq,
                                                   signed char* __restrict__ xq,
                                                   float* __restrict__ gamma,
                                                   float* __restrict__ alpha_out) {
  const int tid = threadIdx.x;
  const int bid = blockIdx.x;
  __shared__ float red[4];
  __shared__ float red2[4];

  if (bid < 4096) {
    const int row = bid;
    const float4* x4 = (const float4*)(x + (size_t)row * 4096);
    const float4* n4 = (const float4*)nw;
    float4 xv[4], nv[4];
#pragma unroll
    for (int i = 0; i < 4; ++i) {
      xv[i] = x4[i * 256 + tid];
      nv[i] = n4[i * 256 + tid];
    }
    float ss = 0.f, mx = 0.f;
#pragma unroll
    for (int i = 0; i < 4; ++i) {
      ss += xv[i].x * xv[i].x + xv[i].y * xv[i].y + xv[i].z * xv[i].z +
            xv[i].w * xv[i].w;
      mx = fmaxf(mx,
                 fmaxf(fmaxf(fabsf(xv[i].x * nv[i].x), fabsf(xv[i].y * nv[i].y)),
                       fmaxf(fabsf(xv[i].z * nv[i].z), fabsf(xv[i].w * nv[i].w))));
    }
    ss = wave_sum(ss);
    mx = wave_max(mx);
    if ((tid & 63) == 0) {
      red[tid >> 6] = ss;
      red2[tid >> 6] = mx;
    }
    __syncthreads();
    const float tot = (red[0] + red[1]) + (red[2] + red[3]);
    const float rms = sqrtf(tot * (1.0f / 4096.0f) + 1e-6f);
    const float mxr = fmaxf(fmaxf(red2[0], red2[1]), fmaxf(red2[2], red2[3]));
    const float g = fmaxf(mxr / rms, 1e-10f);
    if (tid == 0) gamma[row] = g;
    const float inv = 127.0f / (rms * g);

    uint32_t* xqi = (uint32_t*)(xq + (size_t)row * 4096);
#pragma unroll
    for (int i = 0; i < 4; ++i) {
      const int f = i * 256 + tid;
      int q0 = (int)fminf(fmaxf(rintf(xv[i].x * nv[i].x * inv), -128.f), 127.f);
      int q1 = (int)fminf(fmaxf(rintf(xv[i].y * nv[i].y * inv), -128.f), 127.f);
      int q2 = (int)fminf(fmaxf(rintf(xv[i].z * nv[i].z * inv), -128.f), 127.f);
      int q3 = (int)fminf(fmaxf(rintf(xv[i].w * nv[i].w * inv), -128.f), 127.f);
      xqi[f] = (uint32_t)(q0 & 255) | ((uint32_t)(q1 & 255) << 8) |
               ((uint32_t)(q2 & 255) << 16) | ((uint32_t)(q3 & 255) << 24);
    }
  } else {
    const int wb = bid - 4096;
    float s = 0.f;
#pragma unroll
    for (int i = 0; i < 16; ++i) s += part[i * 256 + tid];
    s = wave_sum(s);
    if ((tid & 63) == 0) red[tid >> 6] = s;
    __syncthreads();
    const float alpha =
        fmaxf(((red[0] + red[1]) + (red[2] + red[3])) * (1.0f / 16777216.0f),
              1e-10f);
    if (wb == 0 && tid == 0) alpha_out[0] = alpha;

    const float4* w4 = (const float4*)w;
    uint32_t* wqi = (uint32_t*)wq;
#pragma unroll 1
    for (int k = 0; k < 32; k += 4) {
      const int f0 = (wb * 32 + k) * 256 + tid;
      float4 v0 = w4[f0];
      float4 v1 = w4[f0 + 256];
      float4 v2 = w4[f0 + 512];
      float4 v3 = w4[f0 + 768];
      wqi[f0] = qw4(v0, alpha);
      wqi[f0 + 256] = qw4(v1, alpha);
      wqi[f0 + 512] = qw4(v2, alpha);
      wqi[f0 + 768] = qw4(v3, alpha);
    }
  }
}

// ------------- int8 GEMM: y[m,n] = (xq . wq^T) * alpha*gamma[m]/127 -------
// 256x256 tile, BK=64 (64B/row i8), 8 waves (2M x 4N), per-wave 128x64 output
// = 8x4 frags of 16x16 via mfma_i32_16x16x64_i8 (one MFMA consumes the full
// staged K=64). LDS: 2 dbuf x (A 16K + B 16K) = 64 KiB STATIC shared — no
// dynamic-LDS attribute, no host API in kernel_launch (round-2 failure
// suspect removed).
//
// Phase schedule per K-tile (T3+T4 port): 4 phases x {ds_read 2 A-frags
// (+4 B-frags at p0) || stage-next gl2lds (front-loaded p0/p1) -> raw
// s_barrier -> setprio(1) 8 MFMA setprio(0) -> raw s_barrier}. Per-phase
// barriers carry NO vmcnt drain; the single drain per tile is the end-of-tile
// __syncthreads, giving staged loads ~3 phases (~960 cyc) of MFMA cover over
// ~200 cyc L2-hit latency (k-slices are L2-resident: blocks move in lockstep).
//
// LDS swizzle (BK=64: 4 chunks of 16B per row): LDS chunk p of row R holds
// source chunk p ^ ((R>>1)&3).
//   staging: lane l -> row +(l>>2), LDS pos (l&3), src chunk (l&3)^((l>>3)&3)
//            (4 lanes/row cover a contiguous aligned 64B — coalesced).
//   read: pos = quad ^ ((l16>>1)&3) -> content = src chunk quad = k bytes
//         [quad*16,+16) — matches the verified A/B fragment layout
//         (byte j of 16: k = quad*16 + j; m/n = lane&15).
//   balance: addr mod 128B = (l16&1)*64 + pos*16 -> 8 slots x 8 lanes, the
//   same balanced structure that measured 0 conflicts at BK=128.
// C/D: col = lane&15, row = quad*4 + reg (verified round 0).

#define BM 256
#define BN 256
#define BK 64

__global__ __launch_bounds__(512, 2) void k_gemm(const signed char* __restrict__ xq,
                                                 const signed char* __restrict__ wq,
                                                 const float* __restrict__ gamma,
                                                 const float* __restrict__ alpha_p,
                                                 float* __restrict__ out) {
  __shared__ __align__(16) signed char LDS_[65536];
  const int tid = threadIdx.x;
  const int lane = tid & 63;
  const int wave = tid >> 6;         // 0..7
  const int wm = (wave >> 2) * 128;  // 0 or 128
  const int wn = (wave & 3) * 64;    // 0..192
  const int quad = lane >> 4;
  const int l16 = lane & 15;

  // bijective XCD swizzle: 256 blocks, 8 XCDs -> 32 contiguous per XCD
  const int bid = (blockIdx.x & 7) * 32 + (blockIdx.x >> 3);
  const int bm = (bid >> 4) * BM;
  const int bn = (bid & 15) * BN;

  // staging: wave w, line j (j=0,1) covers rows [(j*8+w)*16, +16).
  // lane l: row +(l>>2), src chunk (l&3)^((l>>3)&3).
  const int lr = lane >> 2;
  const int sc = (lane & 3) ^ ((lane >> 3) & 3);
  const int rb0 = wave * 16;        // line 0 row base
  const int rb1 = (8 + wave) * 16;  // line 1 row base
  const signed char* ag0 = xq + (size_t)(bm + rb0 + lr) * KD + sc * 16;
  const signed char* ag1 = xq + (size_t)(bm + rb1 + lr) * KD + sc * 16;
  const signed char* bg0 = wq + (size_t)(bn + rb0 + lr) * KD + sc * 16;
  const signed char* bg1 = wq + (size_t)(bn + rb1 + lr) * KD + sc * 16;
  const int lA0 = rb0 * BK;  // wave-uniform LDS byte offsets (within buffer)
  const int lA1 = rb1 * BK;

  // ds_read chunk position for this lane's fragments
  const int pos = (quad ^ ((l16 >> 1) & 3)) * 16;

  i32x4 acc[8][4];
#pragma unroll
  for (int i = 0; i < 8; ++i)
#pragma unroll
    for (int j = 0; j < 4; ++j) acc[i][j] = (i32x4){0, 0, 0, 0};

  // ---- prologue: stage tile 0 into buffer 0 ----
  gl2lds16(ag0, LDS_ + lA0);
  gl2lds16(ag1, LDS_ + lA1);
  gl2lds16(bg0, LDS_ + 16384 + lA0);
  gl2lds16(bg1, LDS_ + 16384 + lA1);
  __syncthreads();  // drains vmcnt(0) -> tile 0 resident

  for (int t = 0; t < 64; ++t) {
    const int c = t & 1;
    const signed char* Ab = LDS_ + c * 32768;
    const signed char* Bb = Ab + 16384;
    signed char* An = LDS_ + (c ^ 1) * 32768;
    signed char* Bn = An + 16384;
    const size_t kn = (size_t)(t + 1) * BK;
    const bool more = (t < 63);

    i32x4 bf[4], af[2];

#pragma unroll
    for (int p = 0; p < 4; ++p) {
      // ---- ds_read this phase's fragments ----
      if (p == 0) {
#pragma unroll
        for (int ni = 0; ni < 4; ++ni)
          bf[ni] = *(const i32x4*)&Bb[(wn + ni * 16 + l16) * BK + pos];
      }
#pragma unroll
      for (int j = 0; j < 2; ++j)
        af[j] = *(const i32x4*)&Ab[(wm + (p * 2 + j) * 16 + l16) * BK + pos];

      // ---- stage next tile (front-loaded: A in p0, B in p1) ----
      if (more) {
        if (p == 0) {
          gl2lds16(ag0 + kn, An + lA0);
          gl2lds16(ag1 + kn, An + lA1);
        } else if (p == 1) {
          gl2lds16(bg0 + kn, Bn + lA0);
          gl2lds16(bg1 + kn, Bn + lA1);
        }
      }
      __builtin_amdgcn_s_barrier();  // raw: loads stay in flight
      __builtin_amdgcn_s_setprio(1);
#pragma unroll
      for (int j = 0; j < 2; ++j)
#pragma unroll
        for (int ni = 0; ni < 4; ++ni)
          acc[p * 2 + j][ni] = __builtin_amdgcn_mfma_i32_16x16x64_i8(
              af[j], bf[ni], acc[p * 2 + j][ni], 0, 0, 0);
      __builtin_amdgcn_s_setprio(0);
      if (p < 3) __builtin_amdgcn_s_barrier();
    }
    __syncthreads();  // single per-tile drain: tile t+1 resident
  }

  // ---- epilogue ----
  const float alpha = alpha_p[0];
#pragma unroll
  for (int mi = 0; mi < 8; ++mi) {
#pragma unroll
    for (int r = 0; r < 4; ++r) {
      const int m = bm + wm + mi * 16 + quad * 4 + r;
      const float s = (alpha * gamma[m]) / 127.0f;
#pragma unroll
      for (int ni = 0; ni < 4; ++ni) {
        const int n = bn + wn + ni * 16 + l16;
        out[(size_t)m * ND + n] = (float)acc[mi][ni][r] * s;
      }
    }
  }
}

// --------------------------------------------------------------------------

extern "C" void kernel_launch(void* const* d_in, const int* in_sizes, int n_in,
                              void* d_out, int out_size, void* d_ws, size_t ws_size,
                              hipStream_t stream) {
  const float* x = (const float*)d_in[0];
  const float* w = (const float*)d_in[1];
  const float* nw = (const float*)d_in[2];
  float* out = (float*)d_out;

  char* ws = (char*)d_ws;
  signed char* xq = (signed char*)ws;
  signed char* wq = (signed char*)(ws + ((size_t)1 << 24));
  float* gamma = (float*)(ws + ((size_t)2 << 24));
  float* part = (float*)(ws + ((size_t)2 << 24) + 16384);
  float* alpha = (float*)(ws + ((size_t)2 << 24) + 32768);

  k_alpha_part<<<4096, 256, 0, stream>>>(w, part);
  k_quant_all<<<4096 + WBLK, 256, 0, stream>>>(w, x, nw, part, wq, xq, gamma, alpha);
  k_gemm<<<dim3(256), dim3(512), 0, stream>>>(xq, wq, gamma, alpha, out);
}

// Round 4
// 230.011 us; speedup vs baseline: 1.0649x; 1.0255x over previous
//
#include <hip/hip_runtime.h>
#include <cstdint>
#include <cstddef>

// FusedBitLinear: RMSNorm -> ternary W quant (absmean) -> int8 activation quant
// -> int GEMM (MFMA i8) -> rescale by alpha*gamma[m]/127.
//
// M=4096 tokens, K=4096, N=4096. fp32 in/out.
//
// ws layout:
//   [0, 16M)            xq   int8 [4096][4096]
//   [16M, 32M)          wq   int8 [4096][4096]
//   [32M, +16KB)        gamma float[4096]
//   [+16KB, +32KB)      alpha partials float[4096]
//   [+32KB, +4B)        alpha float[1]

#define KD 4096
#define MD 4096
#define ND 4096

#define WBLK 512

typedef int i32x4 __attribute__((ext_vector_type(4)));

// async global->LDS, 16B per lane; lds dst is wave-uniform base (+lane*16)
__device__ __forceinline__ void gl2lds16(const signed char* g, signed char* l) {
  __builtin_amdgcn_global_load_lds(
      (const __attribute__((address_space(1))) void*)g,
      (__attribute__((address_space(3))) void*)l, 16, 0, 0);
}

__device__ __forceinline__ float wave_sum(float v) {
#pragma unroll
  for (int off = 32; off; off >>= 1) v += __shfl_down(v, off, 64);
  return v;
}
__device__ __forceinline__ float wave_max(float v) {
#pragma unroll
  for (int off = 32; off; off >>= 1) v = fmaxf(v, __shfl_down(v, off, 64));
  return v;
}

// ---------------- pass 1: per-row |W| partial sums (UNCHANGED) ------------

__global__ __launch_bounds__(256) void k_alpha_part(const float* __restrict__ w,
                                                    float* __restrict__ part) {
  __shared__ float red[4];
  const int tid = threadIdx.x;
  const float4* w4 = (const float4*)(w + (size_t)blockIdx.x * 4096);
  float s = 0.f;
#pragma unroll
  for (int i = 0; i < 4; ++i) {
    float4 v = w4[i * 256 + tid];
    s += fabsf(v.x) + fabsf(v.y) + fabsf(v.z) + fabsf(v.w);
  }
  s = wave_sum(s);
  if ((tid & 63) == 0) red[tid >> 6] = s;
  __syncthreads();
  if (tid == 0) part[blockIdx.x] = (red[0] + red[1]) + (red[2] + red[3]);
}

// ---------------- pass 2: fused quantization (UNCHANGED) ------------------

__device__ __forceinline__ uint32_t qw4(float4 v, float alpha) {
  int q0 = (int)fminf(fmaxf(rintf(v.x / alpha), -1.f), 1.f);
  int q1 = (int)fminf(fmaxf(rintf(v.y / alpha), -1.f), 1.f);
  int q2 = (int)fminf(fmaxf(rintf(v.z / alpha), -1.f), 1.f);
  int q3 = (int)fminf(fmaxf(rintf(v.w / alpha), -1.f), 1.f);
  return (uint32_t)(q0 & 255) | ((uint32_t)(q1 & 255) << 8) |
         ((uint32_t)(q2 & 255) << 16) | ((uint32_t)(q3 & 255) << 24);
}

__global__ __launch_bounds__(256) void k_quant_all(const float* __restrict__ w,
                                                   const float* __restrict__ x,
                                                   const float* __restrict__ nw,
                                                   const float* __restrict__ part,
                                                   signed char* __restrict__ wq,
                                                   signed char* __restrict__ xq,
                                                   float* __restrict__ gamma,
                                                   float* __restrict__ alpha_out) {
  const int tid = threadIdx.x;
  const int bid = blockIdx.x;
  __shared__ float red[4];
  __shared__ float red2[4];

  if (bid < 4096) {
    const int row = bid;
    const float4* x4 = (const float4*)(x + (size_t)row * 4096);
    const float4* n4 = (const float4*)nw;
    float4 xv[4], nv[4];
#pragma unroll
    for (int i = 0; i < 4; ++i) {
      xv[i] = x4[i * 256 + tid];
      nv[i] = n4[i * 256 + tid];
    }
    float ss = 0.f, mx = 0.f;
#pragma unroll
    for (int i = 0; i < 4; ++i) {
      ss += xv[i].x * xv[i].x + xv[i].y * xv[i].y + xv[i].z * xv[i].z +
            xv[i].w * xv[i].w;
      mx = fmaxf(mx,
                 fmaxf(fmaxf(fabsf(xv[i].x * nv[i].x), fabsf(xv[i].y * nv[i].y)),
                       fmaxf(fabsf(xv[i].z * nv[i].z), fabsf(xv[i].w * nv[i].w))));
    }
    ss = wave_sum(ss);
    mx = wave_max(mx);
    if ((tid & 63) == 0) {
      red[tid >> 6] = ss;
      red2[tid >> 6] = mx;
    }
    __syncthreads();
    const float tot = (red[0] + red[1]) + (red[2] + red[3]);
    const float rms = sqrtf(tot * (1.0f / 4096.0f) + 1e-6f);
    const float mxr = fmaxf(fmaxf(red2[0], red2[1]), fmaxf(red2[2], red2[3]));
    const float g = fmaxf(mxr / rms, 1e-10f);
    if (tid == 0) gamma[row] = g;
    const float inv = 127.0f / (rms * g);

    uint32_t* xqi = (uint32_t*)(xq + (size_t)row * 4096);
#pragma unroll
    for (int i = 0; i < 4; ++i) {
      const int f = i * 256 + tid;
      int q0 = (int)fminf(fmaxf(rintf(xv[i].x * nv[i].x * inv), -128.f), 127.f);
      int q1 = (int)fminf(fmaxf(rintf(xv[i].y * nv[i].y * inv), -128.f), 127.f);
      int q2 = (int)fminf(fmaxf(rintf(xv[i].z * nv[i].z * inv), -128.f), 127.f);
      int q3 = (int)fminf(fmaxf(rintf(xv[i].w * nv[i].w * inv), -128.f), 127.f);
      xqi[f] = (uint32_t)(q0 & 255) | ((uint32_t)(q1 & 255) << 8) |
               ((uint32_t)(q2 & 255) << 16) | ((uint32_t)(q3 & 255) << 24);
    }
  } else {
    const int wb = bid - 4096;
    float s = 0.f;
#pragma unroll
    for (int i = 0; i < 16; ++i) s += part[i * 256 + tid];
    s = wave_sum(s);
    if ((tid & 63) == 0) red[tid >> 6] = s;
    __syncthreads();
    const float alpha =
        fmaxf(((red[0] + red[1]) + (red[2] + red[3])) * (1.0f / 16777216.0f),
              1e-10f);
    if (wb == 0 && tid == 0) alpha_out[0] = alpha;

    const float4* w4 = (const float4*)w;
    uint32_t* wqi = (uint32_t*)wq;
#pragma unroll 1
    for (int k = 0; k < 32; k += 4) {
      const int f0 = (wb * 32 + k) * 256 + tid;
      float4 v0 = w4[f0];
      float4 v1 = w4[f0 + 256];
      float4 v2 = w4[f0 + 512];
      float4 v3 = w4[f0 + 768];
      wqi[f0] = qw4(v0, alpha);
      wqi[f0 + 256] = qw4(v1, alpha);
      wqi[f0 + 512] = qw4(v2, alpha);
      wqi[f0 + 768] = qw4(v3, alpha);
    }
  }
}

// ------------- int8 GEMM: y[m,n] = (xq . wq^T) * alpha*gamma[m]/127 -------
// 256x256 tile, BK=64, 8 waves (2M x 4N), per-wave 128x64 = 8x4 frags of
// 16x16 via mfma_i32_16x16x64_i8. 64 KiB static LDS double-buffer.
//
// ROUND-4 CHANGE: fully software-pipelined register fragments.
// Old: each phase read its own frags right before its barrier -> every phase
// exposed ~120-150 cyc LDS latency with the MFMA pipe idle (1 block/CU, all
// waves lockstep) -> MfmaUtil stuck at 34%. New: every MFMA consumes frags
// read >= 1 full phase earlier:
//   - A-frags ping-pong af[p&1] (static idx): phase p pre-reads phase p+1's
//     frags BEFORE the phase-p barrier.
//   - B-frags (+ p0 A-frags) for tile t+1 are read at p3 AFTER the
//     vmcnt(0)+barrier that validates the staged buffer, hidden under p3's
//     MFMAs -> no p0 read-bunching stall.
// One raw s_barrier per phase (4/tile). Only drain: per-wave inline-asm
// s_waitcnt vmcnt(0) at p3 pre-barrier (per-wave vmcnt + all-wave barrier =>
// staged buffer fully written). Buffer-reuse safety: last LDS read of tile-t
// data is >=2 barriers before its overwrite issue; all tile-t operands are in
// registers by the time tile-t's buffer is restaged.
//
// Swizzle (verified r3, 0 conflicts): LDS chunk p of row R holds src chunk
// p ^ ((R>>1)&3); staging lane l -> row +(l>>2), pos (l&3), src (l&3)^((l>>3)&3);
// read pos = quad ^ ((l16>>1)&3). A/B frag: byte j: k = quad*16+j, m/n=lane&15.
// C/D: col = lane&15, row = quad*4 + reg (verified r0).

#define BM 256
#define BN 256
#define BK 64

__global__ __launch_bounds__(512, 2) void k_gemm(const signed char* __restrict__ xq,
                                                 const signed char* __restrict__ wq,
                                                 const float* __restrict__ gamma,
                                                 const float* __restrict__ alpha_p,
                                                 float* __restrict__ out) {
  __shared__ __align__(16) signed char LDS_[65536];
  const int tid = threadIdx.x;
  const int lane = tid & 63;
  const int wave = tid >> 6;         // 0..7
  const int wm = (wave >> 2) * 128;  // 0 or 128
  const int wn = (wave & 3) * 64;    // 0..192
  const int quad = lane >> 4;
  const int l16 = lane & 15;

  // bijective XCD swizzle: 256 blocks, 8 XCDs -> 32 contiguous per XCD
  const int bid = (blockIdx.x & 7) * 32 + (blockIdx.x >> 3);
  const int bm = (bid >> 4) * BM;
  const int bn = (bid & 15) * BN;

  // staging: wave w, line j (j=0,1) covers rows [(j*8+w)*16, +16).
  const int lr = lane >> 2;
  const int sc = (lane & 3) ^ ((lane >> 3) & 3);
  const int rb0 = wave * 16;
  const int rb1 = (8 + wave) * 16;
  const signed char* ag0 = xq + (size_t)(bm + rb0 + lr) * KD + sc * 16;
  const signed char* ag1 = xq + (size_t)(bm + rb1 + lr) * KD + sc * 16;
  const signed char* bg0 = wq + (size_t)(bn + rb0 + lr) * KD + sc * 16;
  const signed char* bg1 = wq + (size_t)(bn + rb1 + lr) * KD + sc * 16;
  const int lA0 = rb0 * BK;
  const int lA1 = rb1 * BK;

  const int pos = (quad ^ ((l16 >> 1) & 3)) * 16;

  i32x4 acc[8][4];
#pragma unroll
  for (int i = 0; i < 8; ++i)
#pragma unroll
    for (int j = 0; j < 4; ++j) acc[i][j] = (i32x4){0, 0, 0, 0};

  i32x4 bf[4], bfn[4], af[2][2];

  // ---- prologue: stage tile 0, then preload its B frags + p0 A frags ----
  gl2lds16(ag0, LDS_ + lA0);
  gl2lds16(ag1, LDS_ + lA1);
  gl2lds16(bg0, LDS_ + 16384 + lA0);
  gl2lds16(bg1, LDS_ + 16384 + lA1);
  __syncthreads();  // drains vmcnt(0) -> tile 0 resident
#pragma unroll
  for (int ni = 0; ni < 4; ++ni)
    bf[ni] = *(const i32x4*)&LDS_[16384 + (wn + ni * 16 + l16) * BK + pos];
#pragma unroll
  for (int j = 0; j < 2; ++j)
    af[0][j] = *(const i32x4*)&LDS_[(wm + j * 16 + l16) * BK + pos];

#pragma unroll 2
  for (int t = 0; t < 64; ++t) {
    const int c = t & 1;
    const signed char* Ab = LDS_ + c * 32768;
    signed char* An = LDS_ + (c ^ 1) * 32768;
    signed char* Bn = An + 16384;
    const size_t kn = (size_t)(t + 1) * BK;
    const bool more = (t < 63);

#pragma unroll
    for (int p = 0; p < 4; ++p) {
      // ---- pre-read NEXT phase's A frags from the current buffer ----
      if (p < 3) {
#pragma unroll
        for (int j = 0; j < 2; ++j)
          af[(p + 1) & 1][j] =
              *(const i32x4*)&Ab[(wm + ((p + 1) * 2 + j) * 16 + l16) * BK + pos];
      }
      // ---- stage next tile (A at p0, B at p1); drain at p3 ----
      if (more) {
        if (p == 0) {
          gl2lds16(ag0 + kn, An + lA0);
          gl2lds16(ag1 + kn, An + lA1);
        } else if (p == 1) {
          gl2lds16(bg0 + kn, Bn + lA0);
          gl2lds16(bg1 + kn, Bn + lA1);
        } else if (p == 3) {
          asm volatile("s_waitcnt vmcnt(0)" ::: "memory");
        }
      }
      __builtin_amdgcn_s_barrier();  // one barrier per phase
      // ---- p3 post-barrier: next tile's B frags + p0 A frags (buffer now
      //      valid for ALL waves; hidden under p3's MFMAs) ----
      if (p == 3 && more) {
#pragma unroll
        for (int ni = 0; ni < 4; ++ni)
          bfn[ni] = *(const i32x4*)&Bn[(wn + ni * 16 + l16) * BK + pos];
#pragma unroll
        for (int j = 0; j < 2; ++j)
          af[0][j] = *(const i32x4*)&An[(wm + j * 16 + l16) * BK + pos];
      }
      __builtin_amdgcn_s_setprio(1);
#pragma unroll
      for (int j = 0; j < 2; ++j)
#pragma unroll
        for (int ni = 0; ni < 4; ++ni)
          acc[p * 2 + j][ni] = __builtin_amdgcn_mfma_i32_16x16x64_i8(
              af[p & 1][j], bf[ni], acc[p * 2 + j][ni], 0, 0, 0);
      __builtin_amdgcn_s_setprio(0);
      if (p == 3 && more) {
#pragma unroll
        for (int ni = 0; ni < 4; ++ni) bf[ni] = bfn[ni];
      }
    }
  }

  // ---- epilogue ----
  const float alpha = alpha_p[0];
#pragma unroll
  for (int mi = 0; mi < 8; ++mi) {
#pragma unroll
    for (int r = 0; r < 4; ++r) {
      const int m = bm + wm + mi * 16 + quad * 4 + r;
      const float s = (alpha * gamma[m]) / 127.0f;
#pragma unroll
      for (int ni = 0; ni < 4; ++ni) {
        const int n = bn + wn + ni * 16 + l16;
        out[(size_t)m * ND + n] = (float)acc[mi][ni][r] * s;
      }
    }
  }
}

// --------------------------------------------------------------------------

extern "C" void kernel_launch(void* const* d_in, const int* in_sizes, int n_in,
                              void* d_out, int out_size, void* d_ws, size_t ws_size,
                              hipStream_t stream) {
  const float* x = (const float*)d_in[0];
  const float* w = (const float*)d_in[1];
  const float* nw = (const float*)d_in[2];
  float* out = (float*)d_out;

  char* ws = (char*)d_ws;
  signed char* xq = (signed char*)ws;
  signed char* wq = (signed char*)(ws + ((size_t)1 << 24));
  float* gamma = (float*)(ws + ((size_t)2 << 24));
  float* part = (float*)(ws + ((size_t)2 << 24) + 16384);
  float* alpha = (float*)(ws + ((size_t)2 << 24) + 32768);

  k_alpha_part<<<4096, 256, 0, stream>>>(w, part);
  k_quant_all<<<4096 + WBLK, 256, 0, stream>>>(w, x, nw, part, wq, xq, gamma, alpha);
  k_gemm<<<dim3(256), dim3(512), 0, stream>>>(xq, wq, gamma, alpha, out);
}